// Round 3
// baseline (134.577 us; speedup 1.0000x reference)
//
#include <hip/hip_runtime.h>
#include <hip/hip_bf16.h>

// PGExplainer edge-MLP:
//   logits[e] = relu(concat(emb[src], emb[dst]) @ W1 + b1) @ W2 + b2
// Restructured: A[n] = emb[n] @ W1[:64] + b1 ; B[n] = emb[n] @ W1[64:]
//   logits[e] = relu(A[src]+B[dst]) . W2 + b2
// A,B stored per node as bf16: AB[n*128 + j] (j<64 = A, j>=64 = B).
//
// R2 changes vs R1:
//  - edge: 3 dependent ds_swizzle (LDS pipe, ~100cy each) -> 3 DPP row_shr
//    adds (VALU, ~4cy each); sum lands at sub==7. unroll 2 -> 4 for more
//    gathers in flight (hide L2-miss -> L3 latency on random 128B gathers).
//  - precompute: grid 768 -> 1024 blocks (4096 waves = exact 4 waves/SIMD
//    residency at VGPR<=128, enforced via __launch_bounds__(256,4)).

__device__ __forceinline__ unsigned short f2bf(float f) {
    union { float f; unsigned int i; } v;
    v.f = f;
    unsigned int r = v.i + 0x7fffu + ((v.i >> 16) & 1u);  // RNE
    return (unsigned short)(r >> 16);
}

// dst[l] = src[l - N] within 16-lane rows; OOB lanes get 0 (bound_ctrl).
// We accumulate sums toward the TOP lane of each 8-lane group (sub==7);
// cross-boundary contamination (lane 8 reading lane 7 etc.) only affects
// lanes that are never read for the final result.
__device__ __forceinline__ float dpp_add_shr(float p, const int ctrl_is_1_2_4) {
    // caller passes 1, 2 or 4; map to row_shr:N ctrl = 0x110 | N
    return p;  // (specialized below; kept for clarity)
}

template <int N>
__device__ __forceinline__ float dpp_shr(float x) {
    return __int_as_float(__builtin_amdgcn_update_dpp(
        0, __float_as_int(x), 0x110 | N, 0xf, 0xf, true));
}

// One wave per node. W1 held in 128 VGPRs (fully unrolled -> static indexing).
// emb[n][k] broadcast via v_readlane (VALU pipe, no LDS latency).
__global__ __launch_bounds__(256, 4) void precompute_ab(
    const float* __restrict__ emb, const float* __restrict__ W1,
    const float* __restrict__ b1, unsigned short* __restrict__ AB,
    int nNodes, int totalWaves)
{
    const int lane = threadIdx.x & 63;
    const int waveId = blockIdx.x * (blockDim.x >> 6) + (threadIdx.x >> 6);

    float w1a[64], w1b[64];
#pragma unroll
    for (int k = 0; k < 64; ++k) {
        w1a[k] = W1[k * 64 + lane];          // W1[k][lane]
        w1b[k] = W1[(64 + k) * 64 + lane];   // W1[64+k][lane]
    }
    const float bias = b1[lane];

    int n = waveId;
    if (n >= nNodes) return;
    float e = emb[(size_t)n * 64 + lane];

    while (true) {
        const int n2 = n + totalWaves;
        float e_next = 0.f;
        if (n2 < nNodes) e_next = emb[(size_t)n2 * 64 + lane];  // prefetch

        float accA = bias;
        float accB = 0.f;
#pragma unroll
        for (int k = 0; k < 64; ++k) {
            const float ek = __int_as_float(
                __builtin_amdgcn_readlane(__float_as_int(e), k));
            accA = fmaf(ek, w1a[k], accA);
            accB = fmaf(ek, w1b[k], accB);
        }
        AB[(size_t)n * 128 + lane]      = f2bf(accA);
        AB[(size_t)n * 128 + 64 + lane] = f2bf(accB);

        if (n2 >= nNodes) break;
        n = n2;
        e = e_next;
    }
}

// 8 lanes per edge, 8 edges per wave. Each lane: 8 hidden units via one
// uint4 (16B = 8 bf16) load per operand; 8-lane groups read 128B contiguous
// segments (one full cache line per operand) -> coalesced gather.
// Reduce: 3 DPP row_shr adds, sum at sub==7.
__global__ __launch_bounds__(256) void edge_mlp(
    const int* __restrict__ ei, const unsigned int* __restrict__ AB,
    const float* __restrict__ W2, const float* __restrict__ b2,
    float* __restrict__ out, int nEdges, int totalWaves)
{
    const int lane = threadIdx.x & 63;
    const int sub  = lane & 7;    // hidden-chunk (8 units) within edge
    const int grp  = lane >> 3;   // which of the wave's 8 edges
    const int waveId = blockIdx.x * (blockDim.x >> 6) + (threadIdx.x >> 6);

    float w2v[8];
#pragma unroll
    for (int j = 0; j < 8; ++j) w2v[j] = W2[sub * 8 + j];
    const float b2s = b2[0];
    const int stride = totalWaves * 8;

#pragma unroll 4
    for (int base = waveId * 8; base < nEdges; base += stride) {
        const int e = base + grp;
        const bool valid = (e < nEdges);
        const int ec = valid ? e : 0;

        const int src = ei[ec];
        const int dst = ei[nEdges + ec];

        // A-slice: uints [src*64 + sub*4 ..], B-slice: [dst*64 + 32 + sub*4 ..]
        const uint4 ua = *reinterpret_cast<const uint4*>(AB + (size_t)src * 64 + sub * 4);
        const uint4 ub = *reinterpret_cast<const uint4*>(AB + (size_t)dst * 64 + 32 + sub * 4);

        float p = 0.f;
        const unsigned int au[4] = {ua.x, ua.y, ua.z, ua.w};
        const unsigned int bu[4] = {ub.x, ub.y, ub.z, ub.w};
#pragma unroll
        for (int i = 0; i < 4; ++i) {
            const float alo = __int_as_float((int)(au[i] << 16));
            const float ahi = __int_as_float((int)(au[i] & 0xffff0000u));
            const float blo = __int_as_float((int)(bu[i] << 16));
            const float bhi = __int_as_float((int)(bu[i] & 0xffff0000u));
            const float h0 = fmaxf(alo + blo, 0.f);
            const float h1 = fmaxf(ahi + bhi, 0.f);
            p = fmaf(h0, w2v[2 * i], p);
            p = fmaf(h1, w2v[2 * i + 1], p);
        }

        // reduce over the 8 lanes of this edge: sum accumulates at sub==7.
        p += dpp_shr<1>(p);
        p += dpp_shr<2>(p);
        p += dpp_shr<4>(p);

        if (valid && sub == 7) out[e] = p + b2s;
    }
}

extern "C" void kernel_launch(void* const* d_in, const int* in_sizes, int n_in,
                              void* d_out, int out_size, void* d_ws, size_t ws_size,
                              hipStream_t stream) {
    const float* emb = (const float*)d_in[0];
    const int*   ei  = (const int*)d_in[1];
    const float* W1  = (const float*)d_in[2];
    const float* b1  = (const float*)d_in[3];
    const float* W2  = (const float*)d_in[4];
    const float* b2  = (const float*)d_in[5];
    float* out = (float*)d_out;
    unsigned short* AB = (unsigned short*)d_ws;   // nNodes*128 bf16 = 12.8 MB

    const int nNodes = in_sizes[0] / 64;   // 50000
    const int nEdges = in_sizes[1] / 2;    // 800000

    {
        // VGPR capped at 128 by __launch_bounds__(256,4) -> 4 waves/SIMD;
        // 1024 blocks = 4096 waves = exact full residency.
        const int blocks = 1024;
        precompute_ab<<<blocks, 256, 0, stream>>>(emb, W1, b1, AB, nNodes, blocks * 4);
    }
    {
        // small VGPR -> 8 waves/SIMD; 2048 blocks = 8192 waves full residency
        const int blocks = 2048;
        edge_mlp<<<blocks, 256, 0, stream>>>(ei, (const unsigned int*)AB, W2, b2,
                                             out, nEdges, blocks * 4);
    }
}

// Round 4
// 102.711 us; speedup vs baseline: 1.3103x; 1.3103x over previous
//
#include <hip/hip_runtime.h>
#include <hip/hip_bf16.h>

// PGExplainer edge-MLP:
//   logits[e] = relu(concat(emb[src], emb[dst]) @ W1 + b1) @ W2 + b2
// Restructured: A[n] = emb[n] @ W1[:64] + b1 ; B[n] = emb[n] @ W1[64:]
//   logits[e] = relu(A[src]+B[dst]) . W2 + b2
// AB[n*128 + j] bf16 (j<64 = A, j>=64 = B) lives in d_ws.
//
// R3 changes vs R2:
//  - precompute: scalar readlane loop (serialized VALU->SGPR hazards, plus the
//    R2 launch_bounds spill disaster: VGPR capped 64 -> scratch) -> MFMA
//    16x16x32 bf16 GEMM: [50000x64] @ [64x128]. 16 nodes/wave/iter, W1 held
//    as 16 B-frags (64 VGPRs). NO min-waves launch bound.
//  - edge: unroll 4 -> 8 (16 gathers in flight; test latency vs L3-BW bound).

typedef __attribute__((ext_vector_type(8))) short bf16x8;
typedef __attribute__((ext_vector_type(4))) float f32x4;

__device__ __forceinline__ unsigned short f2bf(float f) {
    union { float f; unsigned int i; } v;
    v.f = f;
    unsigned int r = v.i + 0x7fffu + ((v.i >> 16) & 1u);  // RNE
    return (unsigned short)(r >> 16);
}

template <int N>
__device__ __forceinline__ float dpp_shr(float x) {
    return __int_as_float(__builtin_amdgcn_update_dpp(
        0, __float_as_int(x), 0x110 | N, 0xf, 0xf, true));
}

// MFMA GEMM: C[50000 x 128] = E[50000 x 64] @ Wbig[64 x 128] (+ b1 on cols<64)
// Wbig[k][j'] = j'<64 ? W1[k][j'] : W1[64+k][j'-64].
// Frag layouts (gfx950 mfma_f32_16x16x32_bf16):
//   A: row = lane&15, k = (lane>>4)*8 + i   (8 contiguous bf16 per lane)
//   B: col = lane&15, k = (lane>>4)*8 + i
//   D: col = lane&15, row = (lane>>4)*4 + reg   [verified m89]
__global__ __launch_bounds__(256) void precompute_ab(
    const float* __restrict__ emb, const float* __restrict__ W1,
    const float* __restrict__ b1, unsigned short* __restrict__ AB,
    int nNodes, int totalWaves)
{
    const int lane = threadIdx.x & 63;
    const int waveId = blockIdx.x * (blockDim.x >> 6) + (threadIdx.x >> 6);
    const int c  = lane & 15;   // col (B/D) and row (A) selector
    const int kb = lane >> 4;   // k-block 0..3

    // --- B fragments: 8 n-tiles x 2 k-halves, once per wave ---
    bf16x8 wfrag[8][2];
    float bias[8];
#pragma unroll
    for (int nt = 0; nt < 8; ++nt) {
        const int jp = nt * 16 + c;                       // output col 0..127
        const float* wcol = (jp < 64) ? (W1 + jp) : (W1 + 64 * 64 + (jp - 64));
        bias[nt] = (jp < 64) ? b1[jp] : 0.f;
#pragma unroll
        for (int kk = 0; kk < 2; ++kk) {
#pragma unroll
            for (int i = 0; i < 8; ++i) {
                const int k = kk * 32 + kb * 8 + i;
                wfrag[nt][kk][i] = (short)f2bf(wcol[(size_t)k * 64]);
            }
        }
    }

    for (int n0 = waveId * 16; n0 < nNodes; n0 += totalWaves * 16) {
        // --- A fragments: 16 nodes x 64 k, bf16-converted on the fly ---
        const int arow = n0 + c;
        const int arow_c = (arow < nNodes) ? arow : (nNodes - 1);  // clamp
        const float* erow = emb + (size_t)arow_c * 64 + kb * 8;
        bf16x8 afrag[2];
#pragma unroll
        for (int kk = 0; kk < 2; ++kk) {
            const float4 f0 = *reinterpret_cast<const float4*>(erow + kk * 32);
            const float4 f1 = *reinterpret_cast<const float4*>(erow + kk * 32 + 4);
            afrag[kk][0] = (short)f2bf(f0.x); afrag[kk][1] = (short)f2bf(f0.y);
            afrag[kk][2] = (short)f2bf(f0.z); afrag[kk][3] = (short)f2bf(f0.w);
            afrag[kk][4] = (short)f2bf(f1.x); afrag[kk][5] = (short)f2bf(f1.y);
            afrag[kk][6] = (short)f2bf(f1.z); afrag[kk][7] = (short)f2bf(f1.w);
        }

        f32x4 acc[8];
#pragma unroll
        for (int nt = 0; nt < 8; ++nt) {
            acc[nt][0] = bias[nt]; acc[nt][1] = bias[nt];
            acc[nt][2] = bias[nt]; acc[nt][3] = bias[nt];
        }
#pragma unroll
        for (int kk = 0; kk < 2; ++kk)
#pragma unroll
            for (int nt = 0; nt < 8; ++nt)
                acc[nt] = __builtin_amdgcn_mfma_f32_16x16x32_bf16(
                    afrag[kk], wfrag[nt][kk], acc[nt], 0, 0, 0);

        // --- store: lane writes rows n0 + kb*4 + r, col nt*16 + c ---
        if (n0 + 16 <= nNodes) {
#pragma unroll
            for (int nt = 0; nt < 8; ++nt) {
                const int jp = nt * 16 + c;
#pragma unroll
                for (int r = 0; r < 4; ++r) {
                    const int node = n0 + kb * 4 + r;
                    AB[(size_t)node * 128 + jp] = f2bf(acc[nt][r]);
                }
            }
        } else {
#pragma unroll
            for (int nt = 0; nt < 8; ++nt) {
                const int jp = nt * 16 + c;
#pragma unroll
                for (int r = 0; r < 4; ++r) {
                    const int node = n0 + kb * 4 + r;
                    if (node < nNodes) AB[(size_t)node * 128 + jp] = f2bf(acc[nt][r]);
                }
            }
        }
    }
}

// 8 lanes per edge, 8 edges per wave. Each lane: 8 hidden units via one
// uint4 (16B = 8 bf16) load per operand; 8-lane groups read 128B contiguous
// segments (one cache line per operand). Reduce: 3 DPP row_shr adds -> sub==7.
__global__ __launch_bounds__(256) void edge_mlp(
    const int* __restrict__ ei, const unsigned int* __restrict__ AB,
    const float* __restrict__ W2, const float* __restrict__ b2,
    float* __restrict__ out, int nEdges, int totalWaves)
{
    const int lane = threadIdx.x & 63;
    const int sub  = lane & 7;    // hidden-chunk (8 units) within edge
    const int grp  = lane >> 3;   // which of the wave's 8 edges
    const int waveId = blockIdx.x * (blockDim.x >> 6) + (threadIdx.x >> 6);

    float w2v[8];
#pragma unroll
    for (int j = 0; j < 8; ++j) w2v[j] = W2[sub * 8 + j];
    const float b2s = b2[0];
    const int stride = totalWaves * 8;

#pragma unroll 8
    for (int base = waveId * 8; base < nEdges; base += stride) {
        const int e = base + grp;
        const bool valid = (e < nEdges);
        const int ec = valid ? e : 0;

        const int src = ei[ec];
        const int dst = ei[nEdges + ec];

        const uint4 ua = *reinterpret_cast<const uint4*>(AB + (size_t)src * 64 + sub * 4);
        const uint4 ub = *reinterpret_cast<const uint4*>(AB + (size_t)dst * 64 + 32 + sub * 4);

        float p = 0.f;
        const unsigned int au[4] = {ua.x, ua.y, ua.z, ua.w};
        const unsigned int bu[4] = {ub.x, ub.y, ub.z, ub.w};
#pragma unroll
        for (int i = 0; i < 4; ++i) {
            const float alo = __int_as_float((int)(au[i] << 16));
            const float ahi = __int_as_float((int)(au[i] & 0xffff0000u));
            const float blo = __int_as_float((int)(bu[i] << 16));
            const float bhi = __int_as_float((int)(bu[i] & 0xffff0000u));
            const float h0 = fmaxf(alo + blo, 0.f);
            const float h1 = fmaxf(ahi + bhi, 0.f);
            p = fmaf(h0, w2v[2 * i], p);
            p = fmaf(h1, w2v[2 * i + 1], p);
        }

        // reduce over the 8 lanes of this edge: sum accumulates at sub==7
        // (cross-group DPP contamination only reaches lanes never read).
        p += dpp_shr<1>(p);
        p += dpp_shr<2>(p);
        p += dpp_shr<4>(p);

        if (valid && sub == 7) out[e] = p + b2s;
    }
}

extern "C" void kernel_launch(void* const* d_in, const int* in_sizes, int n_in,
                              void* d_out, int out_size, void* d_ws, size_t ws_size,
                              hipStream_t stream) {
    const float* emb = (const float*)d_in[0];
    const int*   ei  = (const int*)d_in[1];
    const float* W1  = (const float*)d_in[2];
    const float* b1  = (const float*)d_in[3];
    const float* W2  = (const float*)d_in[4];
    const float* b2  = (const float*)d_in[5];
    float* out = (float*)d_out;
    unsigned short* AB = (unsigned short*)d_ws;   // nNodes*128 bf16 = 12.8 MB

    const int nNodes = in_sizes[0] / 64;   // 50000
    const int nEdges = in_sizes[1] / 2;    // 800000

    {
        // 256 blocks = 1024 waves; 16 nodes/wave/iter -> ~3 iters each.
        // More waves would re-read W1 (32KB/wave) for no benefit.
        const int blocks = 256;
        precompute_ab<<<blocks, 256, 0, stream>>>(emb, W1, b1, AB, nNodes, blocks * 4);
    }
    {
        const int blocks = 2048;
        edge_mlp<<<blocks, 256, 0, stream>>>(ei, (const unsigned int*)AB, W2, b2,
                                             out, nEdges, blocks * 4);
    }
}